// Round 25
// baseline (3718.341 us; speedup 1.0000x reference)
//
#include <hip/hip_runtime.h>
#include <hip/hip_bf16.h>

#define D_NODE 300
#define DHID   600
#define NLAYER 5
#define NG     8192
#define BN_EPS 1e-5f
#define KP1    320      // padded K for GEMM1 (300 -> 320)
#define KP2    608      // padded K for GEMM2 (600 -> 608)
#define PER1   (DHID * KP1)    // u16 per W1 plane
#define PER2   (D_NODE * KP2)  // u16 per W2 plane

typedef unsigned short u16;
typedef unsigned int   u32;
typedef unsigned long long u64;
using f32x4   = __attribute__((ext_vector_type(4))) float;
using short8  = __attribute__((ext_vector_type(8))) short;
using short4v = __attribute__((ext_vector_type(4))) short;

// ---- bf16 helpers (RNE) ----
__device__ __forceinline__ float bf2f(u16 u) {
    union { unsigned int i; float f; } v; v.i = ((unsigned int)u) << 16; return v.f;
}
__device__ __forceinline__ u16 f2bf(float f) {
    union { float f; unsigned int i; } v; v.f = f;
    unsigned int x = v.i;
    return (u16)((x + 0x7FFFu + ((x >> 16) & 1u)) >> 16);
}

// ---------------- embed ----------------
__global__ __launch_bounds__(256) void embed_kernel(
    const int* __restrict__ an, const int* __restrict__ ct,
    const float* __restrict__ emb_atom, const float* __restrict__ emb_chir,
    u16* __restrict__ h, long total)
{
    long idx = (long)blockIdx.x * blockDim.x + threadIdx.x;
    if (idx >= total) return;
    int n = (int)(idx / 75);
    int c = (int)(idx % 75);
    int a = an[n], cc = ct[n];
    const float4 av = *(const float4*)&emb_atom[(long)a * D_NODE + c * 4];
    const float4 cv = *(const float4*)&emb_chir[(long)cc * D_NODE + c * 4];
    ushort4 o;
    o.x = f2bf(av.x + cv.x);
    o.y = f2bf(av.y + cv.y);
    o.z = f2bf(av.z + cv.z);
    o.w = f2bf(av.w + cv.w);
    *(ushort4*)&h[(long)n * D_NODE + c * 4] = o;
}

// ---- weight convert+split: [L][2][N][KP]; hi = bf16(W), lo = bf16(W - hi) ----
__global__ __launch_bounds__(256) void wconv_split(
    const float* __restrict__ W, u16* __restrict__ WbT,
    int K, int N, int KP, long per, long total)
{
    long idx = (long)blockIdx.x * blockDim.x + threadIdx.x;
    if (idx >= total) return;
    int l = (int)(idx / per);
    long r = idx % per;
    int n = (int)(r / KP);
    int k = (int)(r % KP);
    float v = (k < K) ? W[(long)l * K * N + (long)k * N + n] : 0.f;
    u16 hi = f2bf(v);
    float lo = v - bf2f(hi);
    WbT[(long)(2 * l) * per + r]     = hi;
    WbT[(long)(2 * l + 1) * per + r] = f2bf(lo);
}

// ---- combined edge tables: comb[l][cm][c] = ebond[l][cm/3][c] + edir[l][cm%3][c] (f32) ----
__global__ __launch_bounds__(256) void comb_kernel(
    const float* __restrict__ ebond, const float* __restrict__ edir,
    float* __restrict__ comb, long total)
{
    long idx = (long)blockIdx.x * blockDim.x + threadIdx.x;
    if (idx >= total) return;               // total = NLAYER*18*75
    int l  = (int)(idx / (18 * 75));
    int r  = (int)(idx % (18 * 75));
    int cm = r / 75;
    int c4 = r % 75;
    const float4 eb = *(const float4*)&ebond[((long)l * 6 + cm / 3) * D_NODE + c4 * 4];
    const float4 ed = *(const float4*)&edir [((long)l * 3 + cm % 3) * D_NODE + c4 * 4];
    float4 o;
    o.x = eb.x + ed.x; o.y = eb.y + ed.y; o.z = eb.z + ed.z; o.w = eb.w + ed.w;
    *(float4*)&comb[((long)l * 18 + cm) * D_NODE + c4 * 4] = o;
}

// ---------------- CSR build ----------------
__global__ __launch_bounds__(256) void zero_int_kernel(int* __restrict__ p, int n)
{
    int i = blockIdx.x * blockDim.x + threadIdx.x;
    if (i < n) p[i] = 0;
}
__global__ __launch_bounds__(256) void count_kernel(
    const int* __restrict__ dst, int* __restrict__ cnt, int E)
{
    int e = blockIdx.x * blockDim.x + threadIdx.x;
    if (e < E) atomicAdd(&cnt[dst[e]], 1);
}
__global__ __launch_bounds__(256) void scan1_kernel(
    const int* __restrict__ cnt, int* __restrict__ bsum, int N)
{
    __shared__ int red[256];
    int b = blockIdx.x, t = threadIdx.x;
    int i0 = b * 1024 + t * 4;
    int s = 0;
    #pragma unroll
    for (int j = 0; j < 4; ++j) { int i = i0 + j; if (i < N) s += cnt[i]; }
    red[t] = s; __syncthreads();
    for (int off = 128; off > 0; off >>= 1) {
        if (t < off) red[t] += red[t + off];
        __syncthreads();
    }
    if (t == 0) bsum[b] = red[0];
}
__global__ void scan2_kernel(int* __restrict__ bsum, int nb)
{
    if (threadIdx.x == 0 && blockIdx.x == 0) {
        int run = 0;
        for (int b = 0; b < nb; ++b) { int v = bsum[b]; bsum[b] = run; run += v; }
    }
}
__global__ __launch_bounds__(256) void scan3_kernel(
    const int* __restrict__ bsum, int* __restrict__ cnt,
    int* __restrict__ row_ptr, int N, int E)
{
    __shared__ int sbuf[256];
    int b = blockIdx.x, t = threadIdx.x;
    int i0 = b * 1024 + t * 4;
    int v[4]; int s = 0;
    #pragma unroll
    for (int j = 0; j < 4; ++j) { int i = i0 + j; v[j] = (i < N) ? cnt[i] : 0; s += v[j]; }
    sbuf[t] = s; __syncthreads();
    for (int off = 1; off < 256; off <<= 1) {
        int add = (t >= off) ? sbuf[t - off] : 0;
        __syncthreads();
        sbuf[t] += add;
        __syncthreads();
    }
    int base = bsum[b] + sbuf[t] - s;
    #pragma unroll
    for (int j = 0; j < 4; ++j) {
        int i = i0 + j;
        if (i < N) { row_ptr[i] = base; cnt[i] = base; base += v[j]; }
    }
    if (b == 0 && t == 0) row_ptr[N] = E;
}
// fill packed edge records: epack = src | (bt*3+bd)<<20   (requires N < 2^20)
__global__ __launch_bounds__(256) void fill_kernel(
    const int* __restrict__ src, const int* __restrict__ bt, const int* __restrict__ bd,
    const int* __restrict__ dst, int* __restrict__ fillp,
    u32* __restrict__ epack, int E)
{
    int e = blockIdx.x * blockDim.x + threadIdx.x;
    if (e < E) {
        int pos = atomicAdd(&fillp[dst[e]], 1);
        epack[pos] = (u32)src[e] | ((u32)(bt[e] * 3 + bd[e]) << 20);
    }
}

// ---------------- agg v2: z[n] = h[n] + sum_in-edges (h[src] + comb[cm]) ----------------
__global__ __launch_bounds__(256) void agg_kernel(
    const u16* __restrict__ h,
    const int* __restrict__ row_ptr, const u32* __restrict__ epack,
    const float* __restrict__ comb,   // [18][300] f32 for this layer
    u16* __restrict__ z, long total)
{
    long idx = (long)blockIdx.x * blockDim.x + threadIdx.x;
    if (idx >= total) return;
    int n = (int)(idx / 75);
    int c = (int)(idx % 75);
    const ushort4 hq = *(const ushort4*)&h[(long)n * D_NODE + c * 4];
    float a0 = bf2f(hq.x), a1 = bf2f(hq.y), a2 = bf2f(hq.z), a3 = bf2f(hq.w);
    int s0 = row_ptr[n], s1 = row_ptr[n + 1];
    for (int i = s0; i < s1; ++i) {
        u32 ep = epack[i];
        int s  = (int)(ep & 0xFFFFFu);
        int cm = (int)(ep >> 20);
        const ushort4 hv = *(const ushort4*)&h[(long)s * D_NODE + c * 4];
        const float4 cv = *(const float4*)&comb[(long)cm * D_NODE + c * 4];
        a0 += bf2f(hv.x) + cv.x;
        a1 += bf2f(hv.y) + cv.y;
        a2 += bf2f(hv.z) + cv.z;
        a3 += bf2f(hv.w) + cv.w;
    }
    ushort4 o;
    o.x = f2bf(a0); o.y = f2bf(a1); o.z = f2bf(a2); o.w = f2bf(a3);
    *(ushort4*)&z[(long)n * D_NODE + c * 4] = o;
}

// ---------------- fused MLP v13: producer-consumer wave specialization ----------------
// 16 waves: waves 0-7 produce T chunks (P1), waves 8-15 consume (P2), Tc[2]
// double-buffered, ONE barrier per chunk. Both wave groups issue MFMAs
// concurrently on every SIMD (breaks the P1->bar->P2->bar lockstep that held
// MfmaUtil at ~21% across R10-R24). Divergent barrier counts match (6 each);
// k-th barriers align as global sync points. Register liveness branch-disjoint
// (p1 producer-only, hacc consumer-only).
__global__ __launch_bounds__(1024, 1) void mlp_fused(
    const u16* __restrict__ Z,
    const u16* __restrict__ W1T,    // [600][320] hi (+PER1 lo, unused)
    const u16* __restrict__ W2T,    // [300][608] hi (+PER2 lo, unused)
    const float* __restrict__ b1, const float* __restrict__ b2,
    const float* __restrict__ bn_g, const float* __restrict__ bn_b,
    const float* __restrict__ bn_m, const float* __restrict__ bn_v,
    u16* __restrict__ Hout, int Nrows, int relu_out)
{
    __shared__ u16 As[128][328];      // 83,968 B (doubles as output staging)
    __shared__ u16 Tc[2][128][136];   // 69,632 B (153,600 total -> 1 block/CU)
    const int tid  = threadIdx.x;
    const int lane = tid & 63;
    const int wid  = tid >> 6;     // wave 0..15
    const int lrow = lane & 15;
    const int kg   = lane >> 4;    // 0..3
    const long r0  = (long)blockIdx.x * 128;
    const short8 zz = (short8){0,0,0,0,0,0,0,0};

    // stage Z tile: 128 rows x 320 k (zero-padded), all 16 waves
    for (int i = tid; i < 128 * 80; i += 1024) {
        int r = i / 80, c4 = i % 80;
        short4v v = (short4v){0, 0, 0, 0};
        if (c4 < 75 && r0 + r < Nrows)
            v = *(const short4v*)&Z[(r0 + r) * D_NODE + c4 * 4];
        *(short4v*)&As[r][c4 * 4] = v;
    }
    __syncthreads();

    if (wid < 8) {
        // ================= PRODUCERS: P1 over 5 chunks =================
        #pragma unroll 1
        for (int tc = 0; tc < 5; ++tc) {
            const int gn1 = tc * 128 + wid * 16 + lrow;
            const bool v1 = (gn1 < DHID);
            const u16* w1p = W1T + (long)gn1 * KP1 + kg * 8;

            f32x4 p1[8];
            #pragma unroll
            for (int m = 0; m < 8; ++m) p1[m] = (f32x4){0.f, 0.f, 0.f, 0.f};

            short8 cwh = v1 ? *(const short8*)(w1p) : zz;

            #pragma unroll
            for (int k0i = 0; k0i < 10; ++k0i) {
                short8 nwh;
                if (k0i < 9) {   // prefetch next k-step's W
                    nwh = v1 ? *(const short8*)(w1p + (k0i + 1) * 32) : zz;
                }
                short8 a[8];
                #pragma unroll
                for (int m = 0; m < 8; ++m)
                    a[m] = *(const short8*)&As[m * 16 + lrow][k0i * 32 + kg * 8];

                __builtin_amdgcn_s_setprio(1);
                #pragma unroll
                for (int m = 0; m < 8; ++m)
                    p1[m] = __builtin_amdgcn_mfma_f32_16x16x32_bf16(a[m], cwh, p1[m], 0, 0, 0);
                __builtin_amdgcn_s_setprio(0);

                if (k0i < 9) { cwh = nwh; }
            }

            // relu + bias -> Tc[tc&1]
            {
                float bias = v1 ? b1[gn1] : 0.f;
                #pragma unroll
                for (int m = 0; m < 8; ++m)
                    #pragma unroll
                    for (int j = 0; j < 4; ++j) {
                        float v = fmaxf(p1[m][j] + bias, 0.f);
                        Tc[tc & 1][m * 16 + kg * 4 + j][wid * 16 + lrow] = f2bf(v);
                    }
            }
            __syncthreads();   // barrier tc (0..4)
        }
        __syncthreads();       // barrier 5 (idle while consumers finish tc=4)
    } else {
        // ================= CONSUMERS: P2 over 5 chunks =================
        const int cw = wid - 8;   // 0..7
        f32x4 hacc[8][3];
        #pragma unroll
        for (int m = 0; m < 8; ++m)
            #pragma unroll
            for (int n = 0; n < 3; ++n)
                hacc[m][n] = (f32x4){0.f, 0.f, 0.f, 0.f};
        const u16* w2p[3]; bool w2v[3];
        #pragma unroll
        for (int nf = 0; nf < 3; ++nf) {
            int gn = cw * 48 + nf * 16 + lrow;
            w2v[nf] = (gn < D_NODE);
            w2p[nf] = W2T + (long)gn * KP2 + kg * 8;
        }
        const bool p2_active = (cw * 48 < D_NODE);   // cw=7 idles

        __syncthreads();       // barrier 0 (wait for Tc[0])
        #pragma unroll 1
        for (int tc = 0; tc < 5; ++tc) {
            if (p2_active) {
                const int kbase = tc * 128;
                const int rb = tc & 1;
                #pragma unroll
                for (int ks = 0; ks < 4; ++ks) {
                    if (kbase + ks * 32 < KP2) {   // k < 608
                        const int kk = kbase + ks * 32;
                        short8 w2h0 = w2v[0] ? *(const short8*)(w2p[0] + kk) : zz;
                        short8 w2h1 = w2v[1] ? *(const short8*)(w2p[1] + kk) : zz;
                        short8 w2h2 = w2v[2] ? *(const short8*)(w2p[2] + kk) : zz;
                        // group 1: rows 0..63 (limits transient pressure)
                        {
                            short8 t0 = *(const short8*)&Tc[rb][ 0 + lrow][ks * 32 + kg * 8];
                            short8 t1 = *(const short8*)&Tc[rb][16 + lrow][ks * 32 + kg * 8];
                            short8 t2 = *(const short8*)&Tc[rb][32 + lrow][ks * 32 + kg * 8];
                            short8 t3 = *(const short8*)&Tc[rb][48 + lrow][ks * 32 + kg * 8];
                            __builtin_amdgcn_s_setprio(1);
                            hacc[0][0] = __builtin_amdgcn_mfma_f32_16x16x32_bf16(t0, w2h0, hacc[0][0], 0, 0, 0);
                            hacc[1][0] = __builtin_amdgcn_mfma_f32_16x16x32_bf16(t1, w2h0, hacc[1][0], 0, 0, 0);
                            hacc[2][0] = __builtin_amdgcn_mfma_f32_16x16x32_bf16(t2, w2h0, hacc[2][0], 0, 0, 0);
                            hacc[3][0] = __builtin_amdgcn_mfma_f32_16x16x32_bf16(t3, w2h0, hacc[3][0], 0, 0, 0);
                            hacc[0][1] = __builtin_amdgcn_mfma_f32_16x16x32_bf16(t0, w2h1, hacc[0][1], 0, 0, 0);
                            hacc[1][1] = __builtin_amdgcn_mfma_f32_16x16x32_bf16(t1, w2h1, hacc[1][1], 0, 0, 0);
                            hacc[2][1] = __builtin_amdgcn_mfma_f32_16x16x32_bf16(t2, w2h1, hacc[2][1], 0, 0, 0);
                            hacc[3][1] = __builtin_amdgcn_mfma_f32_16x16x32_bf16(t3, w2h1, hacc[3][1], 0, 0, 0);
                            hacc[0][2] = __builtin_amdgcn_mfma_f32_16x16x32_bf16(t0, w2h2, hacc[0][2], 0, 0, 0);
                            hacc[1][2] = __builtin_amdgcn_mfma_f32_16x16x32_bf16(t1, w2h2, hacc[1][2], 0, 0, 0);
                            hacc[2][2] = __builtin_amdgcn_mfma_f32_16x16x32_bf16(t2, w2h2, hacc[2][2], 0, 0, 0);
                            hacc[3][2] = __builtin_amdgcn_mfma_f32_16x16x32_bf16(t3, w2h2, hacc[3][2], 0, 0, 0);
                            __builtin_amdgcn_s_setprio(0);
                        }
                        // group 2: rows 64..127
                        {
                            short8 t4 = *(const short8*)&Tc[rb][ 64 + lrow][ks * 32 + kg * 8];
                            short8 t5 = *(const short8*)&Tc[rb][ 80 + lrow][ks * 32 + kg * 8];
                            short8 t6 = *(const short8*)&Tc[rb][ 96 + lrow][ks * 32 + kg * 8];
                            short8 t7 = *(const short8*)&Tc[rb][112 + lrow][ks * 32 + kg * 8];
                            __builtin_amdgcn_s_setprio(1);
                            hacc[4][0] = __builtin_amdgcn_mfma_f32_16x16x32_bf16(t4, w2h0, hacc[4][0], 0, 0, 0);
                            hacc[5][0] = __builtin_amdgcn_mfma_f32_16x16x32_bf16(t5, w2h0, hacc[5][0], 0, 0, 0);
                            hacc[6][0] = __builtin_amdgcn_mfma_f32_16x16x32_bf16(t6, w2h0, hacc[6][0], 0, 0, 0);
                            hacc[7][0] = __builtin_amdgcn_mfma_f32_16x16x32_bf16(t7, w2h0, hacc[7][0], 0, 0, 0);
                            hacc[4][1] = __builtin_amdgcn_mfma_f32_16x16x32_bf16(t4, w2h1, hacc[4][1], 0, 0, 0);
                            hacc[5][1] = __builtin_amdgcn_mfma_f32_16x16x32_bf16(t5, w2h1, hacc[5][1], 0, 0, 0);
                            hacc[6][1] = __builtin_amdgcn_mfma_f32_16x16x32_bf16(t6, w2h1, hacc[6][1], 0, 0, 0);
                            hacc[7][1] = __builtin_amdgcn_mfma_f32_16x16x32_bf16(t7, w2h1, hacc[7][1], 0, 0, 0);
                            hacc[4][2] = __builtin_amdgcn_mfma_f32_16x16x32_bf16(t4, w2h2, hacc[4][2], 0, 0, 0);
                            hacc[5][2] = __builtin_amdgcn_mfma_f32_16x16x32_bf16(t5, w2h2, hacc[5][2], 0, 0, 0);
                            hacc[6][2] = __builtin_amdgcn_mfma_f32_16x16x32_bf16(t6, w2h2, hacc[6][2], 0, 0, 0);
                            hacc[7][2] = __builtin_amdgcn_mfma_f32_16x16x32_bf16(t7, w2h2, hacc[7][2], 0, 0, 0);
                            __builtin_amdgcn_s_setprio(0);
                        }
                    }
                }
            }
            // epilogue staging for the LAST chunk happens before barrier 5;
            // As reads (P1) ended at global barrier 4, so writing As here is safe.
            if (tc == 4 && p2_active) {
                #pragma unroll
                for (int nf = 0; nf < 3; ++nf) {
                    int gn = cw * 48 + nf * 16 + lrow;
                    if (gn < D_NODE) {
                        float bias = b2[gn];
                        float sc = bn_g[gn] * rsqrtf(bn_v[gn] + BN_EPS);
                        float mn = bn_m[gn], bb = bn_b[gn];
                        #pragma unroll
                        for (int m = 0; m < 8; ++m)
                            #pragma unroll
                            for (int j = 0; j < 4; ++j) {
                                float v = hacc[m][nf][j] + bias;
                                v = (v - mn) * sc + bb;
                                if (relu_out) v = fmaxf(v, 0.f);
                                As[m * 16 + kg * 4 + j][gn] = f2bf(v);
                            }
                    }
                }
            }
            __syncthreads();   // barrier tc+1 (1..5)
        }
    }

    // converged: barrier 5 ordered As staging before this copy
    for (int i = tid; i < 128 * 75; i += 1024) {
        int r = i / 75, c4 = i % 75;
        long gr = r0 + r;
        if (gr < Nrows)
            *(ushort4*)&Hout[gr * D_NODE + c4 * 4] = *(const ushort4*)&As[r][c4 * 4];
    }
}

// ---------------- fused pool (sorted gid) + Linear(300,256) ----------------
__device__ __forceinline__ int lower_bound(const int* __restrict__ a, int n, int key)
{
    int lo = 0, hi = n;
    while (lo < hi) { int mid = (lo + hi) >> 1; if (a[mid] < key) lo = mid + 1; else hi = mid; }
    return lo;
}

__global__ __launch_bounds__(256) void pool_head1(
    const u16* __restrict__ h, const int* __restrict__ gid, int N,
    const float* __restrict__ Wt, const float* __restrict__ bt,
    float* __restrict__ x1)
{
    __shared__ float xs[304];
    __shared__ int se[2];
    int g = blockIdx.x;
    int t = threadIdx.x;
    if (t == 0) se[0] = lower_bound(gid, N, g);
    if (t == 1) se[1] = lower_bound(gid, N, g + 1);
    __syncthreads();
    int start = se[0], end = se[1];
    float inv = (end > start) ? 1.0f / (float)(end - start) : 0.f;
    float a0 = 0.f, a1 = 0.f;
    for (int n = start; n < end; ++n) {
        const u16* hp = &h[(long)n * D_NODE];
        a0 += bf2f(hp[t]);
        if (t < 44) a1 += bf2f(hp[256 + t]);
    }
    xs[t] = a0 * inv;
    if (t < 44) xs[256 + t] = a1 * inv;
    __syncthreads();
    float acc = bt[t];
    for (int k = 0; k < D_NODE; ++k)
        acc = fmaf(xs[k], Wt[(long)k * 256 + t], acc);
    x1[(long)g * 256 + t] = acc;
}

// ---------------- head 2: Linear(256,128)+leaky, Linear(128,1) ----------------
__global__ __launch_bounds__(128) void head2_kernel(
    const float* __restrict__ x1,
    const float* __restrict__ Wh, const float* __restrict__ bh,
    const float* __restrict__ Wf, const float* __restrict__ bf,
    float* __restrict__ out, int G)
{
    __shared__ float xs[256];
    __shared__ float red[128];
    int g = blockIdx.x;
    int t = threadIdx.x;
    for (int i = t; i < 256; i += 128) xs[i] = x1[(long)g * 256 + i];
    __syncthreads();
    float acc = bh[t];
    for (int k = 0; k < 256; ++k)
        acc = fmaf(xs[k], Wh[(long)k * 128 + t], acc);
    acc = acc > 0.f ? acc : 0.01f * acc;
    red[t] = acc * Wf[t];
    __syncthreads();
    for (int s = 64; s > 0; s >>= 1) {
        if (t < s) red[t] += red[t + s];
        __syncthreads();
    }
    if (t == 0) out[g] = red[0] + bf[0];
}

extern "C" void kernel_launch(void* const* d_in, const int* in_sizes, int n_in,
                              void* d_out, int out_size, void* d_ws, size_t ws_size,
                              hipStream_t stream)
{
    const int* an   = (const int*)d_in[0];
    const int* ct   = (const int*)d_in[1];
    const int* bt   = (const int*)d_in[2];
    const int* bd   = (const int*)d_in[3];
    const int* src  = (const int*)d_in[4];
    const int* dst  = (const int*)d_in[5];
    const int* gid  = (const int*)d_in[6];
    const float* emb_atom  = (const float*)d_in[8];
    const float* emb_chir  = (const float*)d_in[9];
    const float* edge_bond = (const float*)d_in[10];
    const float* edge_dir  = (const float*)d_in[11];
    const float* W1   = (const float*)d_in[12];
    const float* b1   = (const float*)d_in[13];
    const float* W2   = (const float*)d_in[14];
    const float* b2   = (const float*)d_in[15];
    const float* bn_g = (const float*)d_in[16];
    const float* bn_b = (const float*)d_in[17];
    const float* bn_m = (const float*)d_in[18];
    const float* bn_v = (const float*)d_in[19];
    const float* Wt   = (const float*)d_in[20];
    const float* btr  = (const float*)d_in[21];
    const float* Wh   = (const float*)d_in[22];
    const float* bh   = (const float*)d_in[23];
    const float* Wf   = (const float*)d_in[24];
    const float* bf   = (const float*)d_in[25];

    const long N = in_sizes[0];
    const long E = in_sizes[4];
    const int  G = NG;

    // ---- workspace (~249.2 MB): h | z | WbT1 | WbT2 | comb | row_ptr | epack ----
    char* base = (char*)d_ws;
    size_t off = 0;
    u16* h  = (u16*)(base + off);           off += (size_t)N * D_NODE * 2;
    u16* z  = (u16*)(base + off);           off += (size_t)N * D_NODE * 2;
    u16* WbT1 = (u16*)(base + off);         off += (size_t)NLAYER * 2 * PER1 * 2;
    u16* WbT2 = (u16*)(base + off);         off += (size_t)NLAYER * 2 * PER2 * 2;
    float* comb = (float*)(base + off);     off += (size_t)NLAYER * 18 * D_NODE * 4;
    int* row_ptr = (int*)(base + off);      off += (((size_t)(N + 1) * 4) + 63) & ~(size_t)63;
    u32* epack = (u32*)(base + off);
    // aliases into z (disjoint lifetimes: CSR build pre-embed; x1 post-layers)
    int* row_fill = (int*)z;
    int* bsum     = row_fill + N;
    float* x1     = (float*)z;

    const long nodeTot = N * 75;
    const int  blk = 256;
    const long nodeBlocks = (nodeTot + blk - 1) / blk;
    const int  SB = (int)((N + 1023) / 1024);

    // weights -> split bf16 (hi+lo), transposed, K-padded
    {
        long t1 = (long)NLAYER * PER1;
        wconv_split<<<(t1 + blk - 1) / blk, blk, 0, stream>>>(
            W1, WbT1, D_NODE, DHID, KP1, (long)PER1, t1);
        long t2 = (long)NLAYER * PER2;
        wconv_split<<<(t2 + blk - 1) / blk, blk, 0, stream>>>(
            W2, WbT2, DHID, D_NODE, KP2, (long)PER2, t2);
    }
    // combined edge tables (f32)
    {
        long tc = (long)NLAYER * 18 * 75;
        comb_kernel<<<(tc + blk - 1) / blk, blk, 0, stream>>>(
            edge_bond, edge_dir, comb, tc);
    }

    // CSR build (graph static across layers); packed edge records
    zero_int_kernel<<<((int)N + blk - 1) / blk, blk, 0, stream>>>(row_fill, (int)N);
    count_kernel<<<((int)E + blk - 1) / blk, blk, 0, stream>>>(dst, row_fill, (int)E);
    scan1_kernel<<<SB, blk, 0, stream>>>(row_fill, bsum, (int)N);
    scan2_kernel<<<1, 64, 0, stream>>>(bsum, SB);
    scan3_kernel<<<SB, blk, 0, stream>>>(bsum, row_fill, row_ptr, (int)N, (int)E);
    fill_kernel<<<((int)E + blk - 1) / blk, blk, 0, stream>>>(
        src, bt, bd, dst, row_fill, epack, (int)E);

    embed_kernel<<<nodeBlocks, blk, 0, stream>>>(an, ct, emb_atom, emb_chir, h, nodeTot);

    const int mlpBlocks = (int)((N + 127) / 128);
    for (int l = 0; l < NLAYER; ++l) {
        agg_kernel<<<nodeBlocks, blk, 0, stream>>>(
            h, row_ptr, epack,
            comb + (long)l * 18 * D_NODE,
            z, nodeTot);

        mlp_fused<<<mlpBlocks, 1024, 0, stream>>>(
            z,
            WbT1 + (long)(2 * l) * PER1,
            WbT2 + (long)(2 * l) * PER2,
            b1 + (long)l * DHID, b2 + (long)l * D_NODE,
            bn_g + (long)l * D_NODE, bn_b + (long)l * D_NODE,
            bn_m + (long)l * D_NODE, bn_v + (long)l * D_NODE,
            h, (int)N, (l < NLAYER - 1) ? 1 : 0);
    }

    pool_head1<<<G, 256, 0, stream>>>(h, gid, (int)N, Wt, btr, x1);
    head2_kernel<<<G, 128, 0, stream>>>(x1, Wh, bh, Wf, bf, (float*)d_out, G);
}

// Round 26
// 2573.538 us; speedup vs baseline: 1.4448x; 1.4448x over previous
//
#include <hip/hip_runtime.h>
#include <hip/hip_bf16.h>

#define D_NODE 300
#define DHID   600
#define NLAYER 5
#define NG     8192
#define BN_EPS 1e-5f
#define KP1    320      // padded K for GEMM1 (300 -> 320)
#define KP2    608      // padded K for GEMM2 (600 -> 608)
#define PER1   (DHID * KP1)    // u16 per W1 plane
#define PER2   (D_NODE * KP2)  // u16 per W2 plane

typedef unsigned short u16;
typedef unsigned int   u32;
typedef unsigned long long u64;
using f32x4   = __attribute__((ext_vector_type(4))) float;
using short8  = __attribute__((ext_vector_type(8))) short;
using short4v = __attribute__((ext_vector_type(4))) short;

// ---- bf16 helpers (RNE) ----
__device__ __forceinline__ float bf2f(u16 u) {
    union { unsigned int i; float f; } v; v.i = ((unsigned int)u) << 16; return v.f;
}
__device__ __forceinline__ u16 f2bf(float f) {
    union { float f; unsigned int i; } v; v.f = f;
    unsigned int x = v.i;
    return (u16)((x + 0x7FFFu + ((x >> 16) & 1u)) >> 16);
}

// ---------------- embed ----------------
__global__ __launch_bounds__(256) void embed_kernel(
    const int* __restrict__ an, const int* __restrict__ ct,
    const float* __restrict__ emb_atom, const float* __restrict__ emb_chir,
    u16* __restrict__ h, long total)
{
    long idx = (long)blockIdx.x * blockDim.x + threadIdx.x;
    if (idx >= total) return;
    int n = (int)(idx / 75);
    int c = (int)(idx % 75);
    int a = an[n], cc = ct[n];
    const float4 av = *(const float4*)&emb_atom[(long)a * D_NODE + c * 4];
    const float4 cv = *(const float4*)&emb_chir[(long)cc * D_NODE + c * 4];
    ushort4 o;
    o.x = f2bf(av.x + cv.x);
    o.y = f2bf(av.y + cv.y);
    o.z = f2bf(av.z + cv.z);
    o.w = f2bf(av.w + cv.w);
    *(ushort4*)&h[(long)n * D_NODE + c * 4] = o;
}

// ---- weight convert+split: [L][2][N][KP]; hi = bf16(W), lo = bf16(W - hi) ----
__global__ __launch_bounds__(256) void wconv_split(
    const float* __restrict__ W, u16* __restrict__ WbT,
    int K, int N, int KP, long per, long total)
{
    long idx = (long)blockIdx.x * blockDim.x + threadIdx.x;
    if (idx >= total) return;
    int l = (int)(idx / per);
    long r = idx % per;
    int n = (int)(r / KP);
    int k = (int)(r % KP);
    float v = (k < K) ? W[(long)l * K * N + (long)k * N + n] : 0.f;
    u16 hi = f2bf(v);
    float lo = v - bf2f(hi);
    WbT[(long)(2 * l) * per + r]     = hi;
    WbT[(long)(2 * l + 1) * per + r] = f2bf(lo);
}

// ---- combined edge tables: comb[l][cm][c] = ebond[l][cm/3][c] + edir[l][cm%3][c] (f32) ----
__global__ __launch_bounds__(256) void comb_kernel(
    const float* __restrict__ ebond, const float* __restrict__ edir,
    float* __restrict__ comb, long total)
{
    long idx = (long)blockIdx.x * blockDim.x + threadIdx.x;
    if (idx >= total) return;               // total = NLAYER*18*75
    int l  = (int)(idx / (18 * 75));
    int r  = (int)(idx % (18 * 75));
    int cm = r / 75;
    int c4 = r % 75;
    const float4 eb = *(const float4*)&ebond[((long)l * 6 + cm / 3) * D_NODE + c4 * 4];
    const float4 ed = *(const float4*)&edir [((long)l * 3 + cm % 3) * D_NODE + c4 * 4];
    float4 o;
    o.x = eb.x + ed.x; o.y = eb.y + ed.y; o.z = eb.z + ed.z; o.w = eb.w + ed.w;
    *(float4*)&comb[((long)l * 18 + cm) * D_NODE + c4 * 4] = o;
}

// ---------------- CSR build ----------------
__global__ __launch_bounds__(256) void zero_int_kernel(int* __restrict__ p, int n)
{
    int i = blockIdx.x * blockDim.x + threadIdx.x;
    if (i < n) p[i] = 0;
}
__global__ __launch_bounds__(256) void count_kernel(
    const int* __restrict__ dst, int* __restrict__ cnt, int E)
{
    int e = blockIdx.x * blockDim.x + threadIdx.x;
    if (e < E) atomicAdd(&cnt[dst[e]], 1);
}
__global__ __launch_bounds__(256) void scan1_kernel(
    const int* __restrict__ cnt, int* __restrict__ bsum, int N)
{
    __shared__ int red[256];
    int b = blockIdx.x, t = threadIdx.x;
    int i0 = b * 1024 + t * 4;
    int s = 0;
    #pragma unroll
    for (int j = 0; j < 4; ++j) { int i = i0 + j; if (i < N) s += cnt[i]; }
    red[t] = s; __syncthreads();
    for (int off = 128; off > 0; off >>= 1) {
        if (t < off) red[t] += red[t + off];
        __syncthreads();
    }
    if (t == 0) bsum[b] = red[0];
}
__global__ void scan2_kernel(int* __restrict__ bsum, int nb)
{
    if (threadIdx.x == 0 && blockIdx.x == 0) {
        int run = 0;
        for (int b = 0; b < nb; ++b) { int v = bsum[b]; bsum[b] = run; run += v; }
    }
}
__global__ __launch_bounds__(256) void scan3_kernel(
    const int* __restrict__ bsum, int* __restrict__ cnt,
    int* __restrict__ row_ptr, int N, int E)
{
    __shared__ int sbuf[256];
    int b = blockIdx.x, t = threadIdx.x;
    int i0 = b * 1024 + t * 4;
    int v[4]; int s = 0;
    #pragma unroll
    for (int j = 0; j < 4; ++j) { int i = i0 + j; v[j] = (i < N) ? cnt[i] : 0; s += v[j]; }
    sbuf[t] = s; __syncthreads();
    for (int off = 1; off < 256; off <<= 1) {
        int add = (t >= off) ? sbuf[t - off] : 0;
        __syncthreads();
        sbuf[t] += add;
        __syncthreads();
    }
    int base = bsum[b] + sbuf[t] - s;
    #pragma unroll
    for (int j = 0; j < 4; ++j) {
        int i = i0 + j;
        if (i < N) { row_ptr[i] = base; cnt[i] = base; base += v[j]; }
    }
    if (b == 0 && t == 0) row_ptr[N] = E;
}
// fill packed edge records: epack = src | (bt*3+bd)<<20   (requires N < 2^20)
__global__ __launch_bounds__(256) void fill_kernel(
    const int* __restrict__ src, const int* __restrict__ bt, const int* __restrict__ bd,
    const int* __restrict__ dst, int* __restrict__ fillp,
    u32* __restrict__ epack, int E)
{
    int e = blockIdx.x * blockDim.x + threadIdx.x;
    if (e < E) {
        int pos = atomicAdd(&fillp[dst[e]], 1);
        epack[pos] = (u32)src[e] | ((u32)(bt[e] * 3 + bd[e]) << 20);
    }
}

// ---------------- agg v2: z[n] = h[n] + sum_in-edges (h[src] + comb[cm]) ----------------
__global__ __launch_bounds__(256) void agg_kernel(
    const u16* __restrict__ h,
    const int* __restrict__ row_ptr, const u32* __restrict__ epack,
    const float* __restrict__ comb,   // [18][300] f32 for this layer
    u16* __restrict__ z, long total)
{
    long idx = (long)blockIdx.x * blockDim.x + threadIdx.x;
    if (idx >= total) return;
    int n = (int)(idx / 75);
    int c = (int)(idx % 75);
    const ushort4 hq = *(const ushort4*)&h[(long)n * D_NODE + c * 4];
    float a0 = bf2f(hq.x), a1 = bf2f(hq.y), a2 = bf2f(hq.z), a3 = bf2f(hq.w);
    int s0 = row_ptr[n], s1 = row_ptr[n + 1];
    for (int i = s0; i < s1; ++i) {
        u32 ep = epack[i];
        int s  = (int)(ep & 0xFFFFFu);
        int cm = (int)(ep >> 20);
        const ushort4 hv = *(const ushort4*)&h[(long)s * D_NODE + c * 4];
        const float4 cv = *(const float4*)&comb[(long)cm * D_NODE + c * 4];
        a0 += bf2f(hv.x) + cv.x;
        a1 += bf2f(hv.y) + cv.y;
        a2 += bf2f(hv.z) + cv.z;
        a3 += bf2f(hv.w) + cv.w;
    }
    ushort4 o;
    o.x = f2bf(a0); o.y = f2bf(a1); o.z = f2bf(a2); o.w = f2bf(a3);
    *(ushort4*)&z[(long)n * D_NODE + c * 4] = o;
}

// ---------------- fused MLP v12 (R24 best: 318us, WRITE at ideal 117MB) ----------------
// R25 post-mortem: producer-consumer at 1024thr hit the allocator rule
// VGPR_Count = 65536/blockDim (1024thr -> 64 regs) -> hacc spilled (466MB
// WRITE). Wave specialization is unimplementable under this heuristic; the
// R24 lockstep config is the converged operating point.
__global__ __launch_bounds__(512, 1) void mlp_fused(
    const u16* __restrict__ Z,
    const u16* __restrict__ W1T,    // [600][320] hi (+PER1 lo, unused)
    const u16* __restrict__ W2T,    // [300][608] hi (+PER2 lo, unused)
    const float* __restrict__ b1, const float* __restrict__ b2,
    const float* __restrict__ bn_g, const float* __restrict__ bn_b,
    const float* __restrict__ bn_m, const float* __restrict__ bn_v,
    u16* __restrict__ Hout, int Nrows, int relu_out)
{
    __shared__ u16 As[128][328];   // 83,968 B (doubles as output staging)
    __shared__ u16 Tc[128][136];   // 34,816 B  (118,784 total -> 1 block/CU)
    const int tid  = threadIdx.x;
    const int lane = tid & 63;
    const int w    = tid >> 6;     // wave 0..7
    const int lrow = lane & 15;
    const int kg   = lane >> 4;    // 0..3
    const long r0  = (long)blockIdx.x * 128;
    const short8 zz = (short8){0,0,0,0,0,0,0,0};

    // stage Z tile: 128 rows x 320 k (zero-padded)
    for (int i = tid; i < 128 * 80; i += 512) {
        int r = i / 80, c4 = i % 80;
        short4v v = (short4v){0, 0, 0, 0};
        if (c4 < 75 && r0 + r < Nrows)
            v = *(const short4v*)&Z[(r0 + r) * D_NODE + c4 * 4];
        *(short4v*)&As[r][c4 * 4] = v;
    }
    __syncthreads();

    // P2 state: wave w owns out cols [48w, 48w+48); waves 0..6 active
    f32x4 hacc[8][3];
    #pragma unroll
    for (int m = 0; m < 8; ++m)
        #pragma unroll
        for (int n = 0; n < 3; ++n)
            hacc[m][n] = (f32x4){0.f, 0.f, 0.f, 0.f};
    const u16* w2p[3]; bool w2v[3];
    #pragma unroll
    for (int nf = 0; nf < 3; ++nf) {
        int gn = w * 48 + nf * 16 + lrow;
        w2v[nf] = (gn < D_NODE);
        w2p[nf] = W2T + (long)gn * KP2 + kg * 8;
    }
    const bool p2_active = (w * 48 < D_NODE);

    for (int tc = 0; tc < 5; ++tc) {
        // ---- phase 1: T cols [tc*128, +128); this wave: 16 cols (nf=1), hi-only ----
        const int gn1 = tc * 128 + w * 16 + lrow;
        const bool v1 = (gn1 < DHID);
        const u16* w1p = W1T + (long)gn1 * KP1 + kg * 8;

        f32x4 p1[8];
        #pragma unroll
        for (int m = 0; m < 8; ++m) p1[m] = (f32x4){0.f, 0.f, 0.f, 0.f};

        short8 cwh = v1 ? *(const short8*)(w1p) : zz;

        #pragma unroll
        for (int k0i = 0; k0i < 10; ++k0i) {
            short8 nwh;
            if (k0i < 9) {   // prefetch next k-step's W
                nwh = v1 ? *(const short8*)(w1p + (k0i + 1) * 32) : zz;
            }
            short8 a[8];
            #pragma unroll
            for (int m = 0; m < 8; ++m)
                a[m] = *(const short8*)&As[m * 16 + lrow][k0i * 32 + kg * 8];

            __builtin_amdgcn_s_setprio(1);
            #pragma unroll
            for (int m = 0; m < 8; ++m)
                p1[m] = __builtin_amdgcn_mfma_f32_16x16x32_bf16(a[m], cwh, p1[m], 0, 0, 0);
            __builtin_amdgcn_s_setprio(0);

            if (k0i < 9) { cwh = nwh; }
        }

        // relu + bias -> Tc (bf16); invalid cols produce 0 (zero W/bias)
        {
            float bias = v1 ? b1[gn1] : 0.f;
            #pragma unroll
            for (int m = 0; m < 8; ++m)
                #pragma unroll
                for (int j = 0; j < 4; ++j) {
                    float v = fmaxf(p1[m][j] + bias, 0.f);
                    Tc[m * 16 + kg * 4 + j][w * 16 + lrow] = f2bf(v);
                }
        }
        __syncthreads();

        // ---- phase 2: hacc += Tc @ W2hi[k = tc*128 ...]; this wave: 48 out cols ----
        if (p2_active) {
            const int kbase = tc * 128;
            short8 w2h[3];
            #pragma unroll
            for (int nf = 0; nf < 3; ++nf)
                w2h[nf] = w2v[nf] ? *(const short8*)(w2p[nf] + kbase) : zz;
            #pragma unroll
            for (int ks = 0; ks < 4; ++ks) {
                if (kbase + ks * 32 < KP2) {   // k < 608
                    short8 w2hn[3];
                    const bool pf = (ks < 3) && (kbase + (ks + 1) * 32 < KP2);
                    if (pf) {   // prefetch next ks
                        const int ko = kbase + (ks + 1) * 32;
                        #pragma unroll
                        for (int nf = 0; nf < 3; ++nf)
                            w2hn[nf] = w2v[nf] ? *(const short8*)(w2p[nf] + ko) : zz;
                    }
                    short8 t[8];
                    #pragma unroll
                    for (int m = 0; m < 8; ++m)
                        t[m] = *(const short8*)&Tc[m * 16 + lrow][ks * 32 + kg * 8];
                    __builtin_amdgcn_s_setprio(1);
                    #pragma unroll
                    for (int nf = 0; nf < 3; ++nf)
                        #pragma unroll
                        for (int m = 0; m < 8; ++m)
                            hacc[m][nf] = __builtin_amdgcn_mfma_f32_16x16x32_bf16(t[m], w2h[nf], hacc[m][nf], 0, 0, 0);
                    __builtin_amdgcn_s_setprio(0);
                    if (pf) {
                        #pragma unroll
                        for (int nf = 0; nf < 3; ++nf) { w2h[nf] = w2hn[nf]; }
                    }
                }
            }
        }
        __syncthreads();   // Tc consumed; next chunk may overwrite
    }

    // ---- epilogue: bias + BN (+relu) -> As staging (u16), then coalesced copy ----
    #pragma unroll
    for (int nf = 0; nf < 3; ++nf) {
        int gn = w * 48 + nf * 16 + lrow;
        if (gn < D_NODE) {
            float bias = b2[gn];
            float sc = bn_g[gn] * rsqrtf(bn_v[gn] + BN_EPS);
            float mn = bn_m[gn], bb = bn_b[gn];
            #pragma unroll
            for (int m = 0; m < 8; ++m)
                #pragma unroll
                for (int j = 0; j < 4; ++j) {
                    float v = hacc[m][nf][j] + bias;
                    v = (v - mn) * sc + bb;
                    if (relu_out) v = fmaxf(v, 0.f);
                    As[m * 16 + kg * 4 + j][gn] = f2bf(v);
                }
        }
    }
    __syncthreads();
    // coalesced row-major copy: 128 rows x 75 ushort4
    for (int i = tid; i < 128 * 75; i += 512) {
        int r = i / 75, c4 = i % 75;
        long gr = r0 + r;
        if (gr < Nrows)
            *(ushort4*)&Hout[gr * D_NODE + c4 * 4] = *(const ushort4*)&As[r][c4 * 4];
    }
}

// ---------------- fused pool (sorted gid) + Linear(300,256) ----------------
__device__ __forceinline__ int lower_bound(const int* __restrict__ a, int n, int key)
{
    int lo = 0, hi = n;
    while (lo < hi) { int mid = (lo + hi) >> 1; if (a[mid] < key) lo = mid + 1; else hi = mid; }
    return lo;
}

__global__ __launch_bounds__(256) void pool_head1(
    const u16* __restrict__ h, const int* __restrict__ gid, int N,
    const float* __restrict__ Wt, const float* __restrict__ bt,
    float* __restrict__ x1)
{
    __shared__ float xs[304];
    __shared__ int se[2];
    int g = blockIdx.x;
    int t = threadIdx.x;
    if (t == 0) se[0] = lower_bound(gid, N, g);
    if (t == 1) se[1] = lower_bound(gid, N, g + 1);
    __syncthreads();
    int start = se[0], end = se[1];
    float inv = (end > start) ? 1.0f / (float)(end - start) : 0.f;
    float a0 = 0.f, a1 = 0.f;
    for (int n = start; n < end; ++n) {
        const u16* hp = &h[(long)n * D_NODE];
        a0 += bf2f(hp[t]);
        if (t < 44) a1 += bf2f(hp[256 + t]);
    }
    xs[t] = a0 * inv;
    if (t < 44) xs[256 + t] = a1 * inv;
    __syncthreads();
    float acc = bt[t];
    for (int k = 0; k < D_NODE; ++k)
        acc = fmaf(xs[k], Wt[(long)k * 256 + t], acc);
    x1[(long)g * 256 + t] = acc;
}

// ---------------- head 2: Linear(256,128)+leaky, Linear(128,1) ----------------
__global__ __launch_bounds__(128) void head2_kernel(
    const float* __restrict__ x1,
    const float* __restrict__ Wh, const float* __restrict__ bh,
    const float* __restrict__ Wf, const float* __restrict__ bf,
    float* __restrict__ out, int G)
{
    __shared__ float xs[256];
    __shared__ float red[128];
    int g = blockIdx.x;
    int t = threadIdx.x;
    for (int i = t; i < 256; i += 128) xs[i] = x1[(long)g * 256 + i];
    __syncthreads();
    float acc = bh[t];
    for (int k = 0; k < 256; ++k)
        acc = fmaf(xs[k], Wh[(long)k * 128 + t], acc);
    acc = acc > 0.f ? acc : 0.01f * acc;
    red[t] = acc * Wf[t];
    __syncthreads();
    for (int s = 64; s > 0; s >>= 1) {
        if (t < s) red[t] += red[t + s];
        __syncthreads();
    }
    if (t == 0) out[g] = red[0] + bf[0];
}

extern "C" void kernel_launch(void* const* d_in, const int* in_sizes, int n_in,
                              void* d_out, int out_size, void* d_ws, size_t ws_size,
                              hipStream_t stream)
{
    const int* an   = (const int*)d_in[0];
    const int* ct   = (const int*)d_in[1];
    const int* bt   = (const int*)d_in[2];
    const int* bd   = (const int*)d_in[3];
    const int* src  = (const int*)d_in[4];
    const int* dst  = (const int*)d_in[5];
    const int* gid  = (const int*)d_in[6];
    const float* emb_atom  = (const float*)d_in[8];
    const float* emb_chir  = (const float*)d_in[9];
    const float* edge_bond = (const float*)d_in[10];
    const float* edge_dir  = (const float*)d_in[11];
    const float* W1   = (const float*)d_in[12];
    const float* b1   = (const float*)d_in[13];
    const float* W2   = (const float*)d_in[14];
    const float* b2   = (const float*)d_in[15];
    const float* bn_g = (const float*)d_in[16];
    const float* bn_b = (const float*)d_in[17];
    const float* bn_m = (const float*)d_in[18];
    const float* bn_v = (const float*)d_in[19];
    const float* Wt   = (const float*)d_in[20];
    const float* btr  = (const float*)d_in[21];
    const float* Wh   = (const float*)d_in[22];
    const float* bh   = (const float*)d_in[23];
    const float* Wf   = (const float*)d_in[24];
    const float* bf   = (const float*)d_in[25];

    const long N = in_sizes[0];
    const long E = in_sizes[4];
    const int  G = NG;

    // ---- workspace (~249.2 MB): h | z | WbT1 | WbT2 | comb | row_ptr | epack ----
    char* base = (char*)d_ws;
    size_t off = 0;
    u16* h  = (u16*)(base + off);           off += (size_t)N * D_NODE * 2;
    u16* z  = (u16*)(base + off);           off += (size_t)N * D_NODE * 2;
    u16* WbT1 = (u16*)(base + off);         off += (size_t)NLAYER * 2 * PER1 * 2;
    u16* WbT2 = (u16*)(base + off);         off += (size_t)NLAYER * 2 * PER2 * 2;
    float* comb = (float*)(base + off);     off += (size_t)NLAYER * 18 * D_NODE * 4;
    int* row_ptr = (int*)(base + off);      off += (((size_t)(N + 1) * 4) + 63) & ~(size_t)63;
    u32* epack = (u32*)(base + off);
    // aliases into z (disjoint lifetimes: CSR build pre-embed; x1 post-layers)
    int* row_fill = (int*)z;
    int* bsum     = row_fill + N;
    float* x1     = (float*)z;

    const long nodeTot = N * 75;
    const int  blk = 256;
    const long nodeBlocks = (nodeTot + blk - 1) / blk;
    const int  SB = (int)((N + 1023) / 1024);

    // weights -> split bf16 (hi+lo), transposed, K-padded
    {
        long t1 = (long)NLAYER * PER1;
        wconv_split<<<(t1 + blk - 1) / blk, blk, 0, stream>>>(
            W1, WbT1, D_NODE, DHID, KP1, (long)PER1, t1);
        long t2 = (long)NLAYER * PER2;
        wconv_split<<<(t2 + blk - 1) / blk, blk, 0, stream>>>(
            W2, WbT2, DHID, D_NODE, KP2, (long)PER2, t2);
    }
    // combined edge tables (f32)
    {
        long tc = (long)NLAYER * 18 * 75;
        comb_kernel<<<(tc + blk - 1) / blk, blk, 0, stream>>>(
            edge_bond, edge_dir, comb, tc);
    }

    // CSR build (graph static across layers); packed edge records
    zero_int_kernel<<<((int)N + blk - 1) / blk, blk, 0, stream>>>(row_fill, (int)N);
    count_kernel<<<((int)E + blk - 1) / blk, blk, 0, stream>>>(dst, row_fill, (int)E);
    scan1_kernel<<<SB, blk, 0, stream>>>(row_fill, bsum, (int)N);
    scan2_kernel<<<1, 64, 0, stream>>>(bsum, SB);
    scan3_kernel<<<SB, blk, 0, stream>>>(bsum, row_fill, row_ptr, (int)N, (int)E);
    fill_kernel<<<((int)E + blk - 1) / blk, blk, 0, stream>>>(
        src, bt, bd, dst, row_fill, epack, (int)E);

    embed_kernel<<<nodeBlocks, blk, 0, stream>>>(an, ct, emb_atom, emb_chir, h, nodeTot);

    const int mlpBlocks = (int)((N + 127) / 128);
    for (int l = 0; l < NLAYER; ++l) {
        agg_kernel<<<nodeBlocks, blk, 0, stream>>>(
            h, row_ptr, epack,
            comb + (long)l * 18 * D_NODE,
            z, nodeTot);

        mlp_fused<<<mlpBlocks, 512, 0, stream>>>(
            z,
            WbT1 + (long)(2 * l) * PER1,
            WbT2 + (long)(2 * l) * PER2,
            b1 + (long)l * DHID, b2 + (long)l * D_NODE,
            bn_g + (long)l * D_NODE, bn_b + (long)l * D_NODE,
            bn_m + (long)l * D_NODE, bn_v + (long)l * D_NODE,
            h, (int)N, (l < NLAYER - 1) ? 1 : 0);
    }

    pool_head1<<<G, 256, 0, stream>>>(h, gid, (int)N, Wt, btr, x1);
    head2_kernel<<<G, 128, 0, stream>>>(x1, Wh, bh, Wf, bf, (float*)d_out, G);
}

// Round 27
// 2535.853 us; speedup vs baseline: 1.4663x; 1.0149x over previous
//
#include <hip/hip_runtime.h>
#include <hip/hip_bf16.h>

#define D_NODE 300
#define DHID   600
#define NLAYER 5
#define NG     8192
#define BN_EPS 1e-5f
#define KP1    320      // padded K for GEMM1 (300 -> 320)
#define KP2    608      // padded K for GEMM2 (600 -> 608)
#define PER1   (DHID * KP1)    // u16 per W1 plane
#define PER2   (D_NODE * KP2)  // u16 per W2 plane

typedef unsigned short u16;
typedef unsigned int   u32;
typedef unsigned long long u64;
using f32x4   = __attribute__((ext_vector_type(4))) float;
using short8  = __attribute__((ext_vector_type(8))) short;
using short4v = __attribute__((ext_vector_type(4))) short;

// ---- bf16 helpers (RNE) ----
__device__ __forceinline__ float bf2f(u16 u) {
    union { unsigned int i; float f; } v; v.i = ((unsigned int)u) << 16; return v.f;
}
__device__ __forceinline__ u16 f2bf(float f) {
    union { float f; unsigned int i; } v; v.f = f;
    unsigned int x = v.i;
    return (u16)((x + 0x7FFFu + ((x >> 16) & 1u)) >> 16);
}
// hardware packed f32->bf16 (RNE, gfx950): 1 op per 2 elements vs ~8 for bit-manip
__device__ __forceinline__ u32 cvtpk_bf16(float lo, float hi) {
    u32 r;
    asm("v_cvt_pk_bf16_f32 %0, %1, %2" : "=v"(r) : "v"(lo), "v"(hi));
    return r;
}

// ---------------- embed ----------------
__global__ __launch_bounds__(256) void embed_kernel(
    const int* __restrict__ an, const int* __restrict__ ct,
    const float* __restrict__ emb_atom, const float* __restrict__ emb_chir,
    u16* __restrict__ h, long total)
{
    long idx = (long)blockIdx.x * blockDim.x + threadIdx.x;
    if (idx >= total) return;
    int n = (int)(idx / 75);
    int c = (int)(idx % 75);
    int a = an[n], cc = ct[n];
    const float4 av = *(const float4*)&emb_atom[(long)a * D_NODE + c * 4];
    const float4 cv = *(const float4*)&emb_chir[(long)cc * D_NODE + c * 4];
    ushort4 o;
    o.x = f2bf(av.x + cv.x);
    o.y = f2bf(av.y + cv.y);
    o.z = f2bf(av.z + cv.z);
    o.w = f2bf(av.w + cv.w);
    *(ushort4*)&h[(long)n * D_NODE + c * 4] = o;
}

// ---- weight convert+split: [L][2][N][KP]; hi = bf16(W), lo = bf16(W - hi) ----
__global__ __launch_bounds__(256) void wconv_split(
    const float* __restrict__ W, u16* __restrict__ WbT,
    int K, int N, int KP, long per, long total)
{
    long idx = (long)blockIdx.x * blockDim.x + threadIdx.x;
    if (idx >= total) return;
    int l = (int)(idx / per);
    long r = idx % per;
    int n = (int)(r / KP);
    int k = (int)(r % KP);
    float v = (k < K) ? W[(long)l * K * N + (long)k * N + n] : 0.f;
    u16 hi = f2bf(v);
    float lo = v - bf2f(hi);
    WbT[(long)(2 * l) * per + r]     = hi;
    WbT[(long)(2 * l + 1) * per + r] = f2bf(lo);
}

// ---- combined edge tables: comb[l][cm][c] = ebond[l][cm/3][c] + edir[l][cm%3][c] (f32) ----
__global__ __launch_bounds__(256) void comb_kernel(
    const float* __restrict__ ebond, const float* __restrict__ edir,
    float* __restrict__ comb, long total)
{
    long idx = (long)blockIdx.x * blockDim.x + threadIdx.x;
    if (idx >= total) return;               // total = NLAYER*18*75
    int l  = (int)(idx / (18 * 75));
    int r  = (int)(idx % (18 * 75));
    int cm = r / 75;
    int c4 = r % 75;
    const float4 eb = *(const float4*)&ebond[((long)l * 6 + cm / 3) * D_NODE + c4 * 4];
    const float4 ed = *(const float4*)&edir [((long)l * 3 + cm % 3) * D_NODE + c4 * 4];
    float4 o;
    o.x = eb.x + ed.x; o.y = eb.y + ed.y; o.z = eb.z + ed.z; o.w = eb.w + ed.w;
    *(float4*)&comb[((long)l * 18 + cm) * D_NODE + c4 * 4] = o;
}

// ---------------- CSR build ----------------
__global__ __launch_bounds__(256) void zero_int_kernel(int* __restrict__ p, int n)
{
    int i = blockIdx.x * blockDim.x + threadIdx.x;
    if (i < n) p[i] = 0;
}
__global__ __launch_bounds__(256) void count_kernel(
    const int* __restrict__ dst, int* __restrict__ cnt, int E)
{
    int e = blockIdx.x * blockDim.x + threadIdx.x;
    if (e < E) atomicAdd(&cnt[dst[e]], 1);
}
__global__ __launch_bounds__(256) void scan1_kernel(
    const int* __restrict__ cnt, int* __restrict__ bsum, int N)
{
    __shared__ int red[256];
    int b = blockIdx.x, t = threadIdx.x;
    int i0 = b * 1024 + t * 4;
    int s = 0;
    #pragma unroll
    for (int j = 0; j < 4; ++j) { int i = i0 + j; if (i < N) s += cnt[i]; }
    red[t] = s; __syncthreads();
    for (int off = 128; off > 0; off >>= 1) {
        if (t < off) red[t] += red[t + off];
        __syncthreads();
    }
    if (t == 0) bsum[b] = red[0];
}
__global__ void scan2_kernel(int* __restrict__ bsum, int nb)
{
    if (threadIdx.x == 0 && blockIdx.x == 0) {
        int run = 0;
        for (int b = 0; b < nb; ++b) { int v = bsum[b]; bsum[b] = run; run += v; }
    }
}
__global__ __launch_bounds__(256) void scan3_kernel(
    const int* __restrict__ bsum, int* __restrict__ cnt,
    int* __restrict__ row_ptr, int N, int E)
{
    __shared__ int sbuf[256];
    int b = blockIdx.x, t = threadIdx.x;
    int i0 = b * 1024 + t * 4;
    int v[4]; int s = 0;
    #pragma unroll
    for (int j = 0; j < 4; ++j) { int i = i0 + j; v[j] = (i < N) ? cnt[i] : 0; s += v[j]; }
    sbuf[t] = s; __syncthreads();
    for (int off = 1; off < 256; off <<= 1) {
        int add = (t >= off) ? sbuf[t - off] : 0;
        __syncthreads();
        sbuf[t] += add;
        __syncthreads();
    }
    int base = bsum[b] + sbuf[t] - s;
    #pragma unroll
    for (int j = 0; j < 4; ++j) {
        int i = i0 + j;
        if (i < N) { row_ptr[i] = base; cnt[i] = base; base += v[j]; }
    }
    if (b == 0 && t == 0) row_ptr[N] = E;
}
// fill packed edge records: epack = src | (bt*3+bd)<<20   (requires N < 2^20)
__global__ __launch_bounds__(256) void fill_kernel(
    const int* __restrict__ src, const int* __restrict__ bt, const int* __restrict__ bd,
    const int* __restrict__ dst, int* __restrict__ fillp,
    u32* __restrict__ epack, int E)
{
    int e = blockIdx.x * blockDim.x + threadIdx.x;
    if (e < E) {
        int pos = atomicAdd(&fillp[dst[e]], 1);
        epack[pos] = (u32)src[e] | ((u32)(bt[e] * 3 + bd[e]) << 20);
    }
}

// ---------------- agg v2: z[n] = h[n] + sum_in-edges (h[src] + comb[cm]) ----------------
__global__ __launch_bounds__(256) void agg_kernel(
    const u16* __restrict__ h,
    const int* __restrict__ row_ptr, const u32* __restrict__ epack,
    const float* __restrict__ comb,   // [18][300] f32 for this layer
    u16* __restrict__ z, long total)
{
    long idx = (long)blockIdx.x * blockDim.x + threadIdx.x;
    if (idx >= total) return;
    int n = (int)(idx / 75);
    int c = (int)(idx % 75);
    const ushort4 hq = *(const ushort4*)&h[(long)n * D_NODE + c * 4];
    float a0 = bf2f(hq.x), a1 = bf2f(hq.y), a2 = bf2f(hq.z), a3 = bf2f(hq.w);
    int s0 = row_ptr[n], s1 = row_ptr[n + 1];
    for (int i = s0; i < s1; ++i) {
        u32 ep = epack[i];
        int s  = (int)(ep & 0xFFFFFu);
        int cm = (int)(ep >> 20);
        const ushort4 hv = *(const ushort4*)&h[(long)s * D_NODE + c * 4];
        const float4 cv = *(const float4*)&comb[(long)cm * D_NODE + c * 4];
        a0 += bf2f(hv.x) + cv.x;
        a1 += bf2f(hv.y) + cv.y;
        a2 += bf2f(hv.z) + cv.z;
        a3 += bf2f(hv.w) + cv.w;
    }
    ushort4 o;
    o.x = f2bf(a0); o.y = f2bf(a1); o.z = f2bf(a2); o.w = f2bf(a3);
    *(ushort4*)&z[(long)n * D_NODE + c * 4] = o;
}

// ---------------- fused MLP v13: R24 body + hardware bf16 conversion ----------------
// VALUBusy(23%) >= MfmaUtil(21.6%) at ~2 waves/SIMD: issue slots burned on the
// hand-rolled f2bf (~4 VALU ops/elem, 256 elem/thread). v_cvt_pk_bf16_f32 does
// 2 elem/op with identical RNE semantics -> same bits, fewer issue slots.
__global__ __launch_bounds__(512, 1) void mlp_fused(
    const u16* __restrict__ Z,
    const u16* __restrict__ W1T,    // [600][320] hi (+PER1 lo, unused)
    const u16* __restrict__ W2T,    // [300][608] hi (+PER2 lo, unused)
    const float* __restrict__ b1, const float* __restrict__ b2,
    const float* __restrict__ bn_g, const float* __restrict__ bn_b,
    const float* __restrict__ bn_m, const float* __restrict__ bn_v,
    u16* __restrict__ Hout, int Nrows, int relu_out)
{
    __shared__ u16 As[128][328];   // 83,968 B (doubles as output staging)
    __shared__ u16 Tc[128][136];   // 34,816 B  (118,784 total -> 1 block/CU)
    const int tid  = threadIdx.x;
    const int lane = tid & 63;
    const int w    = tid >> 6;     // wave 0..7
    const int lrow = lane & 15;
    const int kg   = lane >> 4;    // 0..3
    const long r0  = (long)blockIdx.x * 128;
    const short8 zz = (short8){0,0,0,0,0,0,0,0};

    // stage Z tile: 128 rows x 320 k (zero-padded)
    for (int i = tid; i < 128 * 80; i += 512) {
        int r = i / 80, c4 = i % 80;
        short4v v = (short4v){0, 0, 0, 0};
        if (c4 < 75 && r0 + r < Nrows)
            v = *(const short4v*)&Z[(r0 + r) * D_NODE + c4 * 4];
        *(short4v*)&As[r][c4 * 4] = v;
    }
    __syncthreads();

    // P2 state: wave w owns out cols [48w, 48w+48); waves 0..6 active
    f32x4 hacc[8][3];
    #pragma unroll
    for (int m = 0; m < 8; ++m)
        #pragma unroll
        for (int n = 0; n < 3; ++n)
            hacc[m][n] = (f32x4){0.f, 0.f, 0.f, 0.f};
    const u16* w2p[3]; bool w2v[3];
    #pragma unroll
    for (int nf = 0; nf < 3; ++nf) {
        int gn = w * 48 + nf * 16 + lrow;
        w2v[nf] = (gn < D_NODE);
        w2p[nf] = W2T + (long)gn * KP2 + kg * 8;
    }
    const bool p2_active = (w * 48 < D_NODE);

    for (int tc = 0; tc < 5; ++tc) {
        // ---- phase 1: T cols [tc*128, +128); this wave: 16 cols (nf=1), hi-only ----
        const int gn1 = tc * 128 + w * 16 + lrow;
        const bool v1 = (gn1 < DHID);
        const u16* w1p = W1T + (long)gn1 * KP1 + kg * 8;

        f32x4 p1[8];
        #pragma unroll
        for (int m = 0; m < 8; ++m) p1[m] = (f32x4){0.f, 0.f, 0.f, 0.f};

        short8 cwh = v1 ? *(const short8*)(w1p) : zz;

        #pragma unroll
        for (int k0i = 0; k0i < 10; ++k0i) {
            short8 nwh;
            if (k0i < 9) {   // prefetch next k-step's W
                nwh = v1 ? *(const short8*)(w1p + (k0i + 1) * 32) : zz;
            }
            short8 a[8];
            #pragma unroll
            for (int m = 0; m < 8; ++m)
                a[m] = *(const short8*)&As[m * 16 + lrow][k0i * 32 + kg * 8];

            __builtin_amdgcn_s_setprio(1);
            #pragma unroll
            for (int m = 0; m < 8; ++m)
                p1[m] = __builtin_amdgcn_mfma_f32_16x16x32_bf16(a[m], cwh, p1[m], 0, 0, 0);
            __builtin_amdgcn_s_setprio(0);

            if (k0i < 9) { cwh = nwh; }
        }

        // relu + bias -> Tc (bf16 via hw cvt_pk); invalid cols produce 0
        {
            float bias = v1 ? b1[gn1] : 0.f;
            const int col = w * 16 + lrow;
            #pragma unroll
            for (int m = 0; m < 8; ++m) {
                float e0 = fmaxf(p1[m][0] + bias, 0.f);
                float e1 = fmaxf(p1[m][1] + bias, 0.f);
                float e2 = fmaxf(p1[m][2] + bias, 0.f);
                float e3 = fmaxf(p1[m][3] + bias, 0.f);
                u32 p01 = cvtpk_bf16(e0, e1);
                u32 p23 = cvtpk_bf16(e2, e3);
                Tc[m * 16 + kg * 4 + 0][col] = (u16)(p01 & 0xFFFFu);
                Tc[m * 16 + kg * 4 + 1][col] = (u16)(p01 >> 16);
                Tc[m * 16 + kg * 4 + 2][col] = (u16)(p23 & 0xFFFFu);
                Tc[m * 16 + kg * 4 + 3][col] = (u16)(p23 >> 16);
            }
        }
        __syncthreads();

        // ---- phase 2: hacc += Tc @ W2hi[k = tc*128 ...]; this wave: 48 out cols ----
        if (p2_active) {
            const int kbase = tc * 128;
            short8 w2h[3];
            #pragma unroll
            for (int nf = 0; nf < 3; ++nf)
                w2h[nf] = w2v[nf] ? *(const short8*)(w2p[nf] + kbase) : zz;
            #pragma unroll
            for (int ks = 0; ks < 4; ++ks) {
                if (kbase + ks * 32 < KP2) {   // k < 608
                    short8 w2hn[3];
                    const bool pf = (ks < 3) && (kbase + (ks + 1) * 32 < KP2);
                    if (pf) {   // prefetch next ks
                        const int ko = kbase + (ks + 1) * 32;
                        #pragma unroll
                        for (int nf = 0; nf < 3; ++nf)
                            w2hn[nf] = w2v[nf] ? *(const short8*)(w2p[nf] + ko) : zz;
                    }
                    short8 t[8];
                    #pragma unroll
                    for (int m = 0; m < 8; ++m)
                        t[m] = *(const short8*)&Tc[m * 16 + lrow][ks * 32 + kg * 8];
                    __builtin_amdgcn_s_setprio(1);
                    #pragma unroll
                    for (int nf = 0; nf < 3; ++nf)
                        #pragma unroll
                        for (int m = 0; m < 8; ++m)
                            hacc[m][nf] = __builtin_amdgcn_mfma_f32_16x16x32_bf16(t[m], w2h[nf], hacc[m][nf], 0, 0, 0);
                    __builtin_amdgcn_s_setprio(0);
                    if (pf) {
                        #pragma unroll
                        for (int nf = 0; nf < 3; ++nf) { w2h[nf] = w2hn[nf]; }
                    }
                }
            }
        }
        __syncthreads();   // Tc consumed; next chunk may overwrite
    }

    // ---- epilogue: bias + BN (+relu) -> As staging (hw cvt_pk), coalesced copy ----
    #pragma unroll
    for (int nf = 0; nf < 3; ++nf) {
        int gn = w * 48 + nf * 16 + lrow;
        if (gn < D_NODE) {
            float bias = b2[gn];
            float sc = bn_g[gn] * rsqrtf(bn_v[gn] + BN_EPS);
            float mn = bn_m[gn], bb = bn_b[gn];
            #pragma unroll
            for (int m = 0; m < 8; ++m) {
                float e[4];
                #pragma unroll
                for (int j = 0; j < 4; ++j) {
                    float v = hacc[m][nf][j] + bias;
                    v = (v - mn) * sc + bb;
                    if (relu_out) v = fmaxf(v, 0.f);
                    e[j] = v;
                }
                u32 p01 = cvtpk_bf16(e[0], e[1]);
                u32 p23 = cvtpk_bf16(e[2], e[3]);
                As[m * 16 + kg * 4 + 0][gn] = (u16)(p01 & 0xFFFFu);
                As[m * 16 + kg * 4 + 1][gn] = (u16)(p01 >> 16);
                As[m * 16 + kg * 4 + 2][gn] = (u16)(p23 & 0xFFFFu);
                As[m * 16 + kg * 4 + 3][gn] = (u16)(p23 >> 16);
            }
        }
    }
    __syncthreads();
    // coalesced row-major copy: 128 rows x 75 ushort4
    for (int i = tid; i < 128 * 75; i += 512) {
        int r = i / 75, c4 = i % 75;
        long gr = r0 + r;
        if (gr < Nrows)
            *(ushort4*)&Hout[gr * D_NODE + c4 * 4] = *(const ushort4*)&As[r][c4 * 4];
    }
}

// ---------------- fused pool (sorted gid) + Linear(300,256) ----------------
__device__ __forceinline__ int lower_bound(const int* __restrict__ a, int n, int key)
{
    int lo = 0, hi = n;
    while (lo < hi) { int mid = (lo + hi) >> 1; if (a[mid] < key) lo = mid + 1; else hi = mid; }
    return lo;
}

__global__ __launch_bounds__(256) void pool_head1(
    const u16* __restrict__ h, const int* __restrict__ gid, int N,
    const float* __restrict__ Wt, const float* __restrict__ bt,
    float* __restrict__ x1)
{
    __shared__ float xs[304];
    __shared__ int se[2];
    int g = blockIdx.x;
    int t = threadIdx.x;
    if (t == 0) se[0] = lower_bound(gid, N, g);
    if (t == 1) se[1] = lower_bound(gid, N, g + 1);
    __syncthreads();
    int start = se[0], end = se[1];
    float inv = (end > start) ? 1.0f / (float)(end - start) : 0.f;
    float a0 = 0.f, a1 = 0.f;
    for (int n = start; n < end; ++n) {
        const u16* hp = &h[(long)n * D_NODE];
        a0 += bf2f(hp[t]);
        if (t < 44) a1 += bf2f(hp[256 + t]);
    }
    xs[t] = a0 * inv;
    if (t < 44) xs[256 + t] = a1 * inv;
    __syncthreads();
    float acc = bt[t];
    for (int k = 0; k < D_NODE; ++k)
        acc = fmaf(xs[k], Wt[(long)k * 256 + t], acc);
    x1[(long)g * 256 + t] = acc;
}

// ---------------- head 2: Linear(256,128)+leaky, Linear(128,1) ----------------
__global__ __launch_bounds__(128) void head2_kernel(
    const float* __restrict__ x1,
    const float* __restrict__ Wh, const float* __restrict__ bh,
    const float* __restrict__ Wf, const float* __restrict__ bf,
    float* __restrict__ out, int G)
{
    __shared__ float xs[256];
    __shared__ float red[128];
    int g = blockIdx.x;
    int t = threadIdx.x;
    for (int i = t; i < 256; i += 128) xs[i] = x1[(long)g * 256 + i];
    __syncthreads();
    float acc = bh[t];
    for (int k = 0; k < 256; ++k)
        acc = fmaf(xs[k], Wh[(long)k * 128 + t], acc);
    acc = acc > 0.f ? acc : 0.01f * acc;
    red[t] = acc * Wf[t];
    __syncthreads();
    for (int s = 64; s > 0; s >>= 1) {
        if (t < s) red[t] += red[t + s];
        __syncthreads();
    }
    if (t == 0) out[g] = red[0] + bf[0];
}

extern "C" void kernel_launch(void* const* d_in, const int* in_sizes, int n_in,
                              void* d_out, int out_size, void* d_ws, size_t ws_size,
                              hipStream_t stream)
{
    const int* an   = (const int*)d_in[0];
    const int* ct   = (const int*)d_in[1];
    const int* bt   = (const int*)d_in[2];
    const int* bd   = (const int*)d_in[3];
    const int* src  = (const int*)d_in[4];
    const int* dst  = (const int*)d_in[5];
    const int* gid  = (const int*)d_in[6];
    const float* emb_atom  = (const float*)d_in[8];
    const float* emb_chir  = (const float*)d_in[9];
    const float* edge_bond = (const float*)d_in[10];
    const float* edge_dir  = (const float*)d_in[11];
    const float* W1   = (const float*)d_in[12];
    const float* b1   = (const float*)d_in[13];
    const float* W2   = (const float*)d_in[14];
    const float* b2   = (const float*)d_in[15];
    const float* bn_g = (const float*)d_in[16];
    const float* bn_b = (const float*)d_in[17];
    const float* bn_m = (const float*)d_in[18];
    const float* bn_v = (const float*)d_in[19];
    const float* Wt   = (const float*)d_in[20];
    const float* btr  = (const float*)d_in[21];
    const float* Wh   = (const float*)d_in[22];
    const float* bh   = (const float*)d_in[23];
    const float* Wf   = (const float*)d_in[24];
    const float* bf   = (const float*)d_in[25];

    const long N = in_sizes[0];
    const long E = in_sizes[4];
    const int  G = NG;

    // ---- workspace (~249.2 MB): h | z | WbT1 | WbT2 | comb | row_ptr | epack ----
    char* base = (char*)d_ws;
    size_t off = 0;
    u16* h  = (u16*)(base + off);           off += (size_t)N * D_NODE * 2;
    u16* z  = (u16*)(base + off);           off += (size_t)N * D_NODE * 2;
    u16* WbT1 = (u16*)(base + off);         off += (size_t)NLAYER * 2 * PER1 * 2;
    u16* WbT2 = (u16*)(base + off);         off += (size_t)NLAYER * 2 * PER2 * 2;
    float* comb = (float*)(base + off);     off += (size_t)NLAYER * 18 * D_NODE * 4;
    int* row_ptr = (int*)(base + off);      off += (((size_t)(N + 1) * 4) + 63) & ~(size_t)63;
    u32* epack = (u32*)(base + off);
    // aliases into z (disjoint lifetimes: CSR build pre-embed; x1 post-layers)
    int* row_fill = (int*)z;
    int* bsum     = row_fill + N;
    float* x1     = (float*)z;

    const long nodeTot = N * 75;
    const int  blk = 256;
    const long nodeBlocks = (nodeTot + blk - 1) / blk;
    const int  SB = (int)((N + 1023) / 1024);

    // weights -> split bf16 (hi+lo), transposed, K-padded
    {
        long t1 = (long)NLAYER * PER1;
        wconv_split<<<(t1 + blk - 1) / blk, blk, 0, stream>>>(
            W1, WbT1, D_NODE, DHID, KP1, (long)PER1, t1);
        long t2 = (long)NLAYER * PER2;
        wconv_split<<<(t2 + blk - 1) / blk, blk, 0, stream>>>(
            W2, WbT2, DHID, D_NODE, KP2, (long)PER2, t2);
    }
    // combined edge tables (f32)
    {
        long tcn = (long)NLAYER * 18 * 75;
        comb_kernel<<<(tcn + blk - 1) / blk, blk, 0, stream>>>(
            edge_bond, edge_dir, comb, tcn);
    }

    // CSR build (graph static across layers); packed edge records
    zero_int_kernel<<<((int)N + blk - 1) / blk, blk, 0, stream>>>(row_fill, (int)N);
    count_kernel<<<((int)E + blk - 1) / blk, blk, 0, stream>>>(dst, row_fill, (int)E);
    scan1_kernel<<<SB, blk, 0, stream>>>(row_fill, bsum, (int)N);
    scan2_kernel<<<1, 64, 0, stream>>>(bsum, SB);
    scan3_kernel<<<SB, blk, 0, stream>>>(bsum, row_fill, row_ptr, (int)N, (int)E);
    fill_kernel<<<((int)E + blk - 1) / blk, blk, 0, stream>>>(
        src, bt, bd, dst, row_fill, epack, (int)E);

    embed_kernel<<<nodeBlocks, blk, 0, stream>>>(an, ct, emb_atom, emb_chir, h, nodeTot);

    const int mlpBlocks = (int)((N + 127) / 128);
    for (int l = 0; l < NLAYER; ++l) {
        agg_kernel<<<nodeBlocks, blk, 0, stream>>>(
            h, row_ptr, epack,
            comb + (long)l * 18 * D_NODE,
            z, nodeTot);

        mlp_fused<<<mlpBlocks, 512, 0, stream>>>(
            z,
            WbT1 + (long)(2 * l) * PER1,
            WbT2 + (long)(2 * l) * PER2,
            b1 + (long)l * DHID, b2 + (long)l * D_NODE,
            bn_g + (long)l * D_NODE, bn_b + (long)l * D_NODE,
            bn_m + (long)l * D_NODE, bn_v + (long)l * D_NODE,
            h, (int)N, (l < NLAYER - 1) ? 1 : 0);
    }

    pool_head1<<<G, 256, 0, stream>>>(h, gid, (int)N, Wt, btr, x1);
    head2_kernel<<<G, 128, 0, stream>>>(x1, Wh, bh, Wf, bf, (float*)d_out, G);
}